// Round 7
// baseline (19819.814 us; speedup 1.0000x reference)
//
#include <hip/hip_runtime.h>
#include <stdint.h>

// ---------------------------------------------------------------------------
// Problem constants
// ---------------------------------------------------------------------------
#define B   4096
#define F   512
#define H   256
#define E   128
#define V   32000
#define TT  16
#define OC  17          // output columns (16 steps + zero col)
#define NT64 500        // V / 64 : 64-wide v-tiles, W held in registers
#define RQ   4          // row-quads (1024 rows per block)
#define PSTR 6          // floats per partial slot (s, ts, u, la, idx) padded
#define PROWSTR (NT64 * PSTR)   // 3000 floats per row in partial buffer
#define RSCALE 2048.0f
#define RINV   4.8828125e-4f   // 1/2048

typedef _Float16 half8 __attribute__((ext_vector_type(8)));
typedef float f32x4 __attribute__((ext_vector_type(4)));
typedef unsigned short us8 __attribute__((ext_vector_type(8)));

// ---------------------------------------------------------------------------
// Threefry-2x32 (20 rounds) — matches jax._src.prng.threefry2x32 exactly.
// Partitionable counter-mode: bits(i) = x0^x1 at counter (0, i).
// ---------------------------------------------------------------------------
__host__ __device__ __forceinline__ uint32_t tf_rotl(uint32_t x, int r) {
    return (x << r) | (x >> (32 - r));
}

#define TF_R(rot) { x0 += x1; x1 = tf_rotl(x1, rot); x1 ^= x0; }

__host__ __device__ __forceinline__ void tf2x32(uint32_t k0, uint32_t k1,
                                                uint32_t c0, uint32_t c1,
                                                uint32_t& o0, uint32_t& o1) {
    uint32_t k2 = k0 ^ k1 ^ 0x1BD11BDAu;
    uint32_t x0 = c0 + k0, x1 = c1 + k1;
    TF_R(13) TF_R(15) TF_R(26) TF_R(6)
    x0 += k1; x1 += k2 + 1u;
    TF_R(17) TF_R(29) TF_R(16) TF_R(24)
    x0 += k2; x1 += k0 + 2u;
    TF_R(13) TF_R(15) TF_R(26) TF_R(6)
    x0 += k0; x1 += k1 + 3u;
    TF_R(17) TF_R(29) TF_R(16) TF_R(24)
    x0 += k1; x1 += k2 + 4u;
    TF_R(13) TF_R(15) TF_R(26) TF_R(6)
    x0 += k2; x1 += k0 + 5u;
    o0 = x0; o1 = x1;
}

// f16x2 split with SCALED residual: x ~= p1 + p2/2048, p2 = f16(2048*(x-p1)).
__device__ __forceinline__ void split2h(float x, unsigned short& u1, unsigned short& u2) {
    _Float16 a = (_Float16)x;
    float r = (x - (float)a) * RSCALE;
    _Float16 b = (_Float16)r;
    u1 = __builtin_bit_cast(unsigned short, a);
    u2 = __builtin_bit_cast(unsigned short, b);
}

// ---------------------------------------------------------------------------
// init: c=0, inp=broadcast(sos), zero final output column
// ---------------------------------------------------------------------------
__global__ void k_init(float* __restrict__ c, float* __restrict__ inp,
                       const float* __restrict__ sos, float* __restrict__ out) {
    int i = blockIdx.x * 256 + threadIdx.x;
    if (i < B * H) c[i] = 0.f;
    if (i < B * E) inp[i] = sos[i & (E - 1)];
    if (i < 3 * B) {
        int o = i >> 12, r = i & (B - 1);
        out[(size_t)o * (B * OC) + (size_t)r * OC + (OC - 1)] = 0.f;
    }
}

// ---------------------------------------------------------------------------
// h0 = x @ W_in.T + b_in     [4096,256] (fp32 VALU GEMM, runs once)
// ---------------------------------------------------------------------------
__global__ __launch_bounds__(256) void k_h0(const float* __restrict__ x,
                                            const float* __restrict__ W_in,
                                            const float* __restrict__ b_in,
                                            float* __restrict__ h) {
    __shared__ float xs[16 * 512];
    __shared__ float wt[16 * 260];
    const int tid = threadIdx.x;
    const int r0 = blockIdx.x * 16;

#pragma unroll
    for (int p = 0; p < 8; p++) {               // stage x tile [16][512]
        int ff = tid + 256 * p, row = ff >> 7, c4 = ff & 127;
        *(float4*)&xs[row * 512 + c4 * 4] =
            *(const float4*)(x + (size_t)(r0 + row) * 512 + c4 * 4);
    }
    const int g = tid >> 6, l = tid & 63;
    float acc[4][4] = {{0.f}};

    for (int kc = 0; kc < 32; kc++) {
        __syncthreads();
#pragma unroll
        for (int p = 0; p < 4; p++) {           // stage W_in[n][kc*16..] transposed
            int ff = tid + 256 * p, rl = ff >> 2, k4 = ff & 3;
            float4 w = *(const float4*)(W_in + (size_t)rl * 512 + kc * 16 + k4 * 4);
            wt[(k4 * 4 + 0) * 260 + rl] = w.x;
            wt[(k4 * 4 + 1) * 260 + rl] = w.y;
            wt[(k4 * 4 + 2) * 260 + rl] = w.z;
            wt[(k4 * 4 + 3) * 260 + rl] = w.w;
        }
        __syncthreads();
#pragma unroll
        for (int kk = 0; kk < 16; kk += 4) {
            float4 w0 = *(const float4*)&wt[(kk + 0) * 260 + 4 * l];
            float4 w1 = *(const float4*)&wt[(kk + 1) * 260 + 4 * l];
            float4 w2 = *(const float4*)&wt[(kk + 2) * 260 + 4 * l];
            float4 w3 = *(const float4*)&wt[(kk + 3) * 260 + 4 * l];
#pragma unroll
            for (int b = 0; b < 4; b++) {
                float4 xb = *(const float4*)&xs[(4 * g + b) * 512 + kc * 16 + kk];
                acc[b][0] = fmaf(xb.w, w3.x, fmaf(xb.z, w2.x, fmaf(xb.y, w1.x, fmaf(xb.x, w0.x, acc[b][0]))));
                acc[b][1] = fmaf(xb.w, w3.y, fmaf(xb.z, w2.y, fmaf(xb.y, w1.y, fmaf(xb.x, w0.y, acc[b][1]))));
                acc[b][2] = fmaf(xb.w, w3.z, fmaf(xb.z, w2.z, fmaf(xb.y, w1.z, fmaf(xb.x, w0.z, acc[b][2]))));
                acc[b][3] = fmaf(xb.w, w3.w, fmaf(xb.z, w2.w, fmaf(xb.y, w1.w, fmaf(xb.x, w0.w, acc[b][3]))));
            }
        }
    }
    float4 bi = *(const float4*)(b_in + 4 * l);
#pragma unroll
    for (int b = 0; b < 4; b++) {
        float4 o = make_float4(acc[b][0] + bi.x, acc[b][1] + bi.y,
                               acc[b][2] + bi.z, acc[b][3] + bi.w);
        *(float4*)(h + (size_t)(r0 + 4 * g + b) * 256 + 4 * l) = o;
    }
}

// ---------------------------------------------------------------------------
// gates = inp @ W_ih.T + b_ih + h @ W_hh.T + b_hh, fused LSTM cell update,
// + f16x2 split-plane epilogue for the new h. Runs EVERY step (incl. t=0).
// ---------------------------------------------------------------------------
__global__ __launch_bounds__(256) void k_gates_lstm(
    const float* __restrict__ inp, const float* __restrict__ hcur,
    const float* __restrict__ W_ih, const float* __restrict__ W_hh,
    const float* __restrict__ b_ih, const float* __restrict__ b_hh,
    float* __restrict__ c, float* __restrict__ hnxt,
    unsigned short* __restrict__ hsp1, unsigned short* __restrict__ hsp2) {
    __shared__ float xs[16 * 384];
    __shared__ float wt[32 * 260];      // reused as gl[16*256] for the exchange
    const int tid = threadIdx.x;
    const int r0 = blockIdx.x * 16;
    const int u0 = blockIdx.y * 64;

#pragma unroll
    for (int p = 0; p < 2; p++) {               // stage inp [16][128] -> cols [0,128)
        int ff = tid + 256 * p, row = ff >> 5, c4 = ff & 31;
        *(float4*)&xs[row * 384 + c4 * 4] =
            *(const float4*)(inp + (size_t)(r0 + row) * 128 + c4 * 4);
    }
#pragma unroll
    for (int p = 0; p < 4; p++) {               // stage h [16][256] -> cols [128,384)
        int ff = tid + 256 * p, row = ff >> 6, c4 = ff & 63;
        *(float4*)&xs[row * 384 + 128 + c4 * 4] =
            *(const float4*)(hcur + (size_t)(r0 + row) * 256 + c4 * 4);
    }
    const int g = tid >> 6, l = tid & 63;
    float acc[4][4] = {{0.f}};

    for (int kc = 0; kc < 12; kc++) {
        __syncthreads();
        {
            const float* src; int rowlen, koff;
            if (kc < 4) { src = W_ih; rowlen = 128; koff = kc * 32; }
            else        { src = W_hh; rowlen = 256; koff = (kc - 4) * 32; }
#pragma unroll
            for (int p = 0; p < 8; p++) {
                int rl = (tid >> 3) + 32 * p;   // row_local 0..255
                int k4 = tid & 7;
                int grow = ((rl >> 6) << 8) + u0 + (rl & 63);
                float4 w = *(const float4*)(src + (size_t)grow * rowlen + koff + k4 * 4);
                wt[(k4 * 4 + 0) * 260 + rl] = w.x;
                wt[(k4 * 4 + 1) * 260 + rl] = w.y;
                wt[(k4 * 4 + 2) * 260 + rl] = w.z;
                wt[(k4 * 4 + 3) * 260 + rl] = w.w;
            }
        }
        __syncthreads();
#pragma unroll
        for (int kk = 0; kk < 32; kk += 4) {
            float4 w0 = *(const float4*)&wt[(kk + 0) * 260 + 4 * l];
            float4 w1 = *(const float4*)&wt[(kk + 1) * 260 + 4 * l];
            float4 w2 = *(const float4*)&wt[(kk + 2) * 260 + 4 * l];
            float4 w3 = *(const float4*)&wt[(kk + 3) * 260 + 4 * l];
#pragma unroll
            for (int b = 0; b < 4; b++) {
                float4 xb = *(const float4*)&xs[(4 * g + b) * 384 + kc * 32 + kk];
                acc[b][0] = fmaf(xb.w, w3.x, fmaf(xb.z, w2.x, fmaf(xb.y, w1.x, fmaf(xb.x, w0.x, acc[b][0]))));
                acc[b][1] = fmaf(xb.w, w3.y, fmaf(xb.z, w2.y, fmaf(xb.y, w1.y, fmaf(xb.x, w0.y, acc[b][1]))));
                acc[b][2] = fmaf(xb.w, w3.z, fmaf(xb.z, w2.z, fmaf(xb.y, w1.z, fmaf(xb.x, w0.z, acc[b][2]))));
                acc[b][3] = fmaf(xb.w, w3.w, fmaf(xb.z, w2.w, fmaf(xb.y, w1.w, fmaf(xb.x, w0.w, acc[b][3]))));
            }
        }
    }
    {
        int rl0 = 4 * l;
        int grow0 = ((rl0 >> 6) << 8) + u0 + (rl0 & 63);
        float4 bi = *(const float4*)(b_ih + grow0);
        float4 bh = *(const float4*)(b_hh + grow0);
#pragma unroll
        for (int b = 0; b < 4; b++) {
            acc[b][0] += bi.x + bh.x; acc[b][1] += bi.y + bh.y;
            acc[b][2] += bi.z + bh.z; acc[b][3] += bi.w + bh.w;
        }
    }
    __syncthreads();
    float* gl = wt;                              // [16][256]: gate*64+ul per row
#pragma unroll
    for (int b = 0; b < 4; b++)
        *(float4*)&gl[(4 * g + b) * 256 + 4 * l] =
            make_float4(acc[b][0], acc[b][1], acc[b][2], acc[b][3]);
    __syncthreads();
    {   // LSTM pointwise: thread -> (bl = tid>>4, 4 u's)
        int bl = tid >> 4, uq = tid & 15;
        size_t cidx = (size_t)(r0 + bl) * 256 + u0 + uq * 4;
        float4 cold4 = *(float4*)(c + cidx);
        float4 cv, hv;
#pragma unroll
        for (int j = 0; j < 4; j++) {
            int ul = uq * 4 + j;
            float gi = gl[bl * 256 + ul];
            float gf = gl[bl * 256 + 64 + ul];
            float gg = gl[bl * 256 + 128 + ul];
            float go = gl[bl * 256 + 192 + ul];
            float si = fmaf(0.5f, tanhf(0.5f * gi), 0.5f);
            float sf = fmaf(0.5f, tanhf(0.5f * gf), 0.5f);
            float so = fmaf(0.5f, tanhf(0.5f * go), 0.5f);
            float tg = tanhf(gg);
            float cold = (&cold4.x)[j];
            float cn = sf * cold + si * tg;
            (&cv.x)[j] = cn;
            (&hv.x)[j] = so * tanhf(cn);
        }
        *(float4*)(c + cidx) = cv;
        *(float4*)(hnxt + cidx) = hv;
        ushort4 p1, p2;
        split2h(hv.x, p1.x, p2.x);
        split2h(hv.y, p1.y, p2.y);
        split2h(hv.z, p1.z, p2.z);
        split2h(hv.w, p1.w, p2.w);
        *(ushort4*)(hsp1 + cidx) = p1;
        *(ushort4*)(hsp2 + cidx) = p2;
    }
}

// ---------------------------------------------------------------------------
// W-STATIONARY fused logits + gumbel + per-(tile,row) partials.
// Block = 64-v tile x 1024 rows. Wave w owns v = tile*64 + w*16 + n4 (one v
// per thread). W fragments (both split planes, 8 kc) live in REGISTERS,
// split from fp32 on the fly. A (h split planes, 4MB total, L2-resident)
// is read as MFMA fragments directly from global each row-group.
// MFMA chain per element is BITWISE IDENTICAL to the round-4 passing kernel:
//   ah: 8x (a1*b1) over kc ; al: per kc (a1*b2 ; a2*b1) ; lg = ah + al/2048 + bo
// Per row-group: 16-lane butterfly + cross-wave LDS combine -> one partial
// per (tile, row): [s, ts, u, la, idx].
// ---------------------------------------------------------------------------
__global__ __launch_bounds__(256, 3) void k_logits_sample(
    const unsigned short* __restrict__ hsp1, const unsigned short* __restrict__ hsp2,
    const float* __restrict__ W_out, const float* __restrict__ b_out,
    unsigned key0, unsigned key1, float* __restrict__ part) {
    __shared__ float red[4][32][5];
    const int tid = threadIdx.x;
    const int w = tid >> 6, lane = tid & 63;
    const int quad = lane >> 4, n4 = lane & 15;
    const int tile = blockIdx.x % NT64;
    const int q    = blockIdx.x / NT64;
    const int v    = tile * 64 + w * 16 + n4;

    // ---- W fragments: load fp32, split to two f16 planes, keep in regs ----
    half8 b1[8], b2[8];
#pragma unroll
    for (int kc = 0; kc < 8; kc++) {
        const float* wp = W_out + (size_t)v * 256 + kc * 32 + quad * 8;
        float4 wa = *(const float4*)wp;
        float4 wb = *(const float4*)(wp + 4);
        float wv[8] = {wa.x, wa.y, wa.z, wa.w, wb.x, wb.y, wb.z, wb.w};
#pragma unroll
        for (int j = 0; j < 8; j++) {
            _Float16 hi = (_Float16)wv[j];
            float r = (wv[j] - (float)hi) * RSCALE;
            b1[kc][j] = hi;
            b2[kc][j] = (_Float16)r;
        }
    }
    const float bo = b_out[v];

#pragma unroll 1
    for (int rg = 0; rg < 32; rg++) {
        const int r0 = q * 1024 + rg * 32;
        f32x4 ah[2], al[2];
#pragma unroll
        for (int mt = 0; mt < 2; mt++) {
            ah[mt] = (f32x4){0.f, 0.f, 0.f, 0.f};
            al[mt] = (f32x4){0.f, 0.f, 0.f, 0.f};
        }
#pragma unroll
        for (int kc = 0; kc < 8; kc++) {
            // A-frags straight from global (L2-hot): A[m=n4][k=quad*8+j]
            size_t abase = (size_t)(r0 + n4) * 256 + kc * 32 + quad * 8;
            half8 a1m0 = *(const half8*)(hsp1 + abase);
            half8 a1m1 = *(const half8*)(hsp1 + abase + 16 * 256);
            half8 a2m0 = *(const half8*)(hsp2 + abase);
            half8 a2m1 = *(const half8*)(hsp2 + abase + 16 * 256);
            ah[0] = __builtin_amdgcn_mfma_f32_16x16x32_f16(a1m0, b1[kc], ah[0], 0, 0, 0);
            al[0] = __builtin_amdgcn_mfma_f32_16x16x32_f16(a1m0, b2[kc], al[0], 0, 0, 0);
            al[0] = __builtin_amdgcn_mfma_f32_16x16x32_f16(a2m0, b1[kc], al[0], 0, 0, 0);
            ah[1] = __builtin_amdgcn_mfma_f32_16x16x32_f16(a1m1, b1[kc], ah[1], 0, 0, 0);
            al[1] = __builtin_amdgcn_mfma_f32_16x16x32_f16(a1m1, b2[kc], al[1], 0, 0, 0);
            al[1] = __builtin_amdgcn_mfma_f32_16x16x32_f16(a2m1, b1[kc], al[1], 0, 0, 0);
        }
        // ---- epilogue + immediate per-row reduction ----
#pragma unroll
        for (int mt = 0; mt < 2; mt++) {
#pragma unroll
            for (int j = 0; j < 4; j++) {
                float lg = fmaf(RINV, al[mt][j], ah[mt][j]) + bo;
                float e = __expf(lg - 20.f);
                float ts = fmaf(e, lg, 0.f);
                unsigned row = (unsigned)(r0 + mt * 16 + quad * 4 + j);
                unsigned o0, o1;
                tf2x32(key0, key1, 0u, row * (unsigned)V + (unsigned)v, o0, o1);
                unsigned bits = o0 ^ o1;
                float f = __uint_as_float((bits >> 9) | 0x3f800000u) - 1.0f;
                float uu = fmaxf(1.17549435e-38f, f + 1.17549435e-38f);
                float gmb = -logf(-logf(uu));
                float ut = lg + gmb;
                float s = e, la = lg; int ai = v;
                // butterfly over the 16 lanes (n4) sharing this row
#pragma unroll
                for (int off = 1; off < 16; off <<= 1) {
                    s  += __shfl_xor(s, off);
                    ts += __shfl_xor(ts, off);
                    float u2 = __shfl_xor(ut, off);
                    float la2 = __shfl_xor(la, off);
                    int a2 = __shfl_xor(ai, off);
                    if (u2 > ut || (u2 == ut && a2 < ai)) { ut = u2; ai = a2; la = la2; }
                }
                if (n4 == 0) {
                    int rl = mt * 16 + quad * 4 + j;
                    red[w][rl][0] = s;
                    red[w][rl][1] = ts;
                    red[w][rl][2] = ut;
                    red[w][rl][3] = la;
                    ((int*)red[w][rl])[4] = ai;
                }
            }
        }
        __syncthreads();
        if (tid < 32) {
            float s = red[0][tid][0] + red[1][tid][0] + red[2][tid][0] + red[3][tid][0];
            float ts = red[0][tid][1] + red[1][tid][1] + red[2][tid][1] + red[3][tid][1];
            float ut = red[0][tid][2];
            float la = red[0][tid][3];
            int ai = ((int*)red[0][tid])[4];
#pragma unroll
            for (int w2 = 1; w2 < 4; w2++) {
                float u2 = red[w2][tid][2];
                int a2 = ((int*)red[w2][tid])[4];
                if (u2 > ut || (u2 == ut && a2 < ai)) {
                    ut = u2; ai = a2; la = red[w2][tid][3];
                }
            }
            float* p = part + (size_t)(r0 + tid) * PROWSTR + tile * PSTR;
            p[0] = s; p[1] = ts; p[2] = ut; p[3] = la;
            ((int*)p)[4] = ai;
        }
        __syncthreads();
    }
}

// ---------------------------------------------------------------------------
// Combine NT64 partials per row -> sample, logp, entropy, emb gather.
// block: 8 rows x 32 lanes; lane-split slots + 32-lane butterfly.
// ---------------------------------------------------------------------------
__global__ __launch_bounds__(256) void k_sample_out(
    const float* __restrict__ part, const float* __restrict__ emb,
    float* __restrict__ inp, float* __restrict__ out, int step) {
    const int tid = threadIdx.x;
    const int row = blockIdx.x * 8 + (tid >> 5);
    const int lane = tid & 31;
    const float* p = part + (size_t)row * PROWSTR;
    float s = 0.f, ts = 0.f, ut = -3.4e38f, la = 0.f; int a = 0;
    for (int cg = lane; cg < NT64; cg += 32) {
        const float* qq = p + cg * PSTR;
        s += qq[0]; ts += qq[1];
        float uc = qq[2]; int ac = ((const int*)qq)[4];
        if (uc > ut || (uc == ut && ac < a)) { ut = uc; a = ac; la = qq[3]; }
    }
#pragma unroll
    for (int off = 1; off < 32; off <<= 1) {
        s  += __shfl_xor(s, off);
        ts += __shfl_xor(ts, off);
        float u2 = __shfl_xor(ut, off);
        float la2 = __shfl_xor(la, off);
        int a2 = __shfl_xor(a, off);
        if (u2 > ut || (u2 == ut && a2 < a)) { ut = u2; a = a2; la = la2; }
    }
    float lse = logf(s) + 20.f;
    if (lane == 0) {
        out[(size_t)row * OC + step] = (float)a;
        out[(size_t)B * OC + (size_t)row * OC + step] = la - lse;
        out[(size_t)2 * B * OC + (size_t)row * OC + step] = lse - ts / s;
    }
    float4 e4 = *(const float4*)(emb + (size_t)a * 128 + lane * 4);
    *(float4*)&inp[(size_t)row * 128 + lane * 4] = e4;
}

// ---------------------------------------------------------------------------
// Host — LSTM cell runs EVERY step (incl. t=0), then logits from the NEW h.
// ---------------------------------------------------------------------------
extern "C" void kernel_launch(void* const* d_in, const int* in_sizes, int n_in,
                              void* d_out, int out_size, void* d_ws, size_t ws_size,
                              hipStream_t stream) {
    (void)in_sizes; (void)n_in; (void)out_size; (void)ws_size;
    const float* x     = (const float*)d_in[0];
    const float* W_in  = (const float*)d_in[1];
    const float* b_in  = (const float*)d_in[2];
    const float* W_out = (const float*)d_in[3];
    const float* b_out = (const float*)d_in[4];
    const float* emb   = (const float*)d_in[5];
    const float* sos   = (const float*)d_in[6];
    const float* W_ih  = (const float*)d_in[7];
    const float* W_hh  = (const float*)d_in[8];
    const float* b_ih  = (const float*)d_in[9];
    const float* b_hh  = (const float*)d_in[10];
    float* out = (float*)d_out;
    float* ws  = (float*)d_ws;

    float* hA   = ws;                                   // B*H f32
    float* hB   = ws + 1048576;                         // B*H f32
    float* cc   = ws + 2097152;                         // B*H f32
    float* inp  = ws + 3145728;                         // B*E f32
    float* part = ws + 3670016;                         // B * PROWSTR f32 = 12.288M
    unsigned short* hsp1 = (unsigned short*)(ws + 15958016);  // B*H ushort
    unsigned short* hsp2 = (unsigned short*)(ws + 16482304);  // B*H ushort
    // total ~68 MB — within the workspace footprint proven in rounds 1-6

    // step keys: foldlike split of key(42) = (0,42): key_t = block at (0, t)
    unsigned K0[TT], K1[TT];
    for (int t = 0; t < TT; t++) {
        uint32_t o0, o1;
        tf2x32(0u, 42u, 0u, (uint32_t)t, o0, o1);
        K0[t] = o0; K1[t] = o1;
    }

    k_init<<<4096, 256, 0, stream>>>(cc, inp, sos, out);
    k_h0<<<B / 16, 256, 0, stream>>>(x, W_in, b_in, hA);

    float* hc = hA;
    float* hn = hB;
    for (int t = 0; t < TT; t++) {
        k_gates_lstm<<<dim3(B / 16, 4), 256, 0, stream>>>(inp, hc, W_ih, W_hh,
                                                          b_ih, b_hh, cc, hn, hsp1, hsp2);
        k_logits_sample<<<NT64 * RQ, 256, 0, stream>>>(hsp1, hsp2, W_out, b_out,
                                                       K0[t], K1[t], part);
        k_sample_out<<<B / 8, 256, 0, stream>>>(part, emb, inp, out, t);
        float* tmp = hc; hc = hn; hn = tmp;
    }
}

// Round 8
// 17157.648 us; speedup vs baseline: 1.1552x; 1.1552x over previous
//
#include <hip/hip_runtime.h>
#include <stdint.h>

// ---------------------------------------------------------------------------
// Problem constants
// ---------------------------------------------------------------------------
#define B   4096
#define F   512
#define H   256
#define E   128
#define V   32000
#define TT  16
#define OC  17          // output columns (16 steps + zero col)
#define NT64 500        // V / 64 : 64-wide v-tiles, W held in registers
#define RQ   4          // row-quads (1024 rows per block)
#define PSTR 6          // floats per partial slot (s, ts, u, la, idx) padded
#define PROWSTR (NT64 * PSTR)   // 3000 floats per row in partial buffer
#define RSCALE 2048.0f
#define RINV   4.8828125e-4f   // 1/2048

typedef _Float16 half8 __attribute__((ext_vector_type(8)));
typedef float f32x4 __attribute__((ext_vector_type(4)));
typedef unsigned short us8 __attribute__((ext_vector_type(8)));

// ---------------------------------------------------------------------------
// Threefry-2x32 (20 rounds) — matches jax._src.prng.threefry2x32 exactly.
// Partitionable counter-mode: bits(i) = x0^x1 at counter (0, i).
// ---------------------------------------------------------------------------
__host__ __device__ __forceinline__ uint32_t tf_rotl(uint32_t x, int r) {
    return (x << r) | (x >> (32 - r));
}

#define TF_R(rot) { x0 += x1; x1 = tf_rotl(x1, rot); x1 ^= x0; }

__host__ __device__ __forceinline__ void tf2x32(uint32_t k0, uint32_t k1,
                                                uint32_t c0, uint32_t c1,
                                                uint32_t& o0, uint32_t& o1) {
    uint32_t k2 = k0 ^ k1 ^ 0x1BD11BDAu;
    uint32_t x0 = c0 + k0, x1 = c1 + k1;
    TF_R(13) TF_R(15) TF_R(26) TF_R(6)
    x0 += k1; x1 += k2 + 1u;
    TF_R(17) TF_R(29) TF_R(16) TF_R(24)
    x0 += k2; x1 += k0 + 2u;
    TF_R(13) TF_R(15) TF_R(26) TF_R(6)
    x0 += k0; x1 += k1 + 3u;
    TF_R(17) TF_R(29) TF_R(16) TF_R(24)
    x0 += k1; x1 += k2 + 4u;
    TF_R(13) TF_R(15) TF_R(26) TF_R(6)
    x0 += k2; x1 += k0 + 5u;
    o0 = x0; o1 = x1;
}

// f16x2 split with SCALED residual: x ~= p1 + p2/2048, p2 = f16(2048*(x-p1)).
__device__ __forceinline__ void split2h(float x, unsigned short& u1, unsigned short& u2) {
    _Float16 a = (_Float16)x;
    float r = (x - (float)a) * RSCALE;
    _Float16 b = (_Float16)r;
    u1 = __builtin_bit_cast(unsigned short, a);
    u2 = __builtin_bit_cast(unsigned short, b);
}

// ---------------------------------------------------------------------------
// init: c=0, inp=broadcast(sos), zero final output column
// ---------------------------------------------------------------------------
__global__ void k_init(float* __restrict__ c, float* __restrict__ inp,
                       const float* __restrict__ sos, float* __restrict__ out) {
    int i = blockIdx.x * 256 + threadIdx.x;
    if (i < B * H) c[i] = 0.f;
    if (i < B * E) inp[i] = sos[i & (E - 1)];
    if (i < 3 * B) {
        int o = i >> 12, r = i & (B - 1);
        out[(size_t)o * (B * OC) + (size_t)r * OC + (OC - 1)] = 0.f;
    }
}

// ---------------------------------------------------------------------------
// h0 = x @ W_in.T + b_in     [4096,256] (fp32 VALU GEMM, runs once)
// ---------------------------------------------------------------------------
__global__ __launch_bounds__(256) void k_h0(const float* __restrict__ x,
                                            const float* __restrict__ W_in,
                                            const float* __restrict__ b_in,
                                            float* __restrict__ h) {
    __shared__ float xs[16 * 512];
    __shared__ float wt[16 * 260];
    const int tid = threadIdx.x;
    const int r0 = blockIdx.x * 16;

#pragma unroll
    for (int p = 0; p < 8; p++) {               // stage x tile [16][512]
        int ff = tid + 256 * p, row = ff >> 7, c4 = ff & 127;
        *(float4*)&xs[row * 512 + c4 * 4] =
            *(const float4*)(x + (size_t)(r0 + row) * 512 + c4 * 4);
    }
    const int g = tid >> 6, l = tid & 63;
    float acc[4][4] = {{0.f}};

    for (int kc = 0; kc < 32; kc++) {
        __syncthreads();
#pragma unroll
        for (int p = 0; p < 4; p++) {           // stage W_in[n][kc*16..] transposed
            int ff = tid + 256 * p, rl = ff >> 2, k4 = ff & 3;
            float4 w = *(const float4*)(W_in + (size_t)rl * 512 + kc * 16 + k4 * 4);
            wt[(k4 * 4 + 0) * 260 + rl] = w.x;
            wt[(k4 * 4 + 1) * 260 + rl] = w.y;
            wt[(k4 * 4 + 2) * 260 + rl] = w.z;
            wt[(k4 * 4 + 3) * 260 + rl] = w.w;
        }
        __syncthreads();
#pragma unroll
        for (int kk = 0; kk < 16; kk += 4) {
            float4 w0 = *(const float4*)&wt[(kk + 0) * 260 + 4 * l];
            float4 w1 = *(const float4*)&wt[(kk + 1) * 260 + 4 * l];
            float4 w2 = *(const float4*)&wt[(kk + 2) * 260 + 4 * l];
            float4 w3 = *(const float4*)&wt[(kk + 3) * 260 + 4 * l];
#pragma unroll
            for (int b = 0; b < 4; b++) {
                float4 xb = *(const float4*)&xs[(4 * g + b) * 512 + kc * 16 + kk];
                acc[b][0] = fmaf(xb.w, w3.x, fmaf(xb.z, w2.x, fmaf(xb.y, w1.x, fmaf(xb.x, w0.x, acc[b][0]))));
                acc[b][1] = fmaf(xb.w, w3.y, fmaf(xb.z, w2.y, fmaf(xb.y, w1.y, fmaf(xb.x, w0.y, acc[b][1]))));
                acc[b][2] = fmaf(xb.w, w3.z, fmaf(xb.z, w2.z, fmaf(xb.y, w1.z, fmaf(xb.x, w0.z, acc[b][2]))));
                acc[b][3] = fmaf(xb.w, w3.w, fmaf(xb.z, w2.w, fmaf(xb.y, w1.w, fmaf(xb.x, w0.w, acc[b][3]))));
            }
        }
    }
    float4 bi = *(const float4*)(b_in + 4 * l);
#pragma unroll
    for (int b = 0; b < 4; b++) {
        float4 o = make_float4(acc[b][0] + bi.x, acc[b][1] + bi.y,
                               acc[b][2] + bi.z, acc[b][3] + bi.w);
        *(float4*)(h + (size_t)(r0 + 4 * g + b) * 256 + 4 * l) = o;
    }
}

// ---------------------------------------------------------------------------
// gates = inp @ W_ih.T + b_ih + h @ W_hh.T + b_hh, fused LSTM cell update,
// + f16x2 split-plane epilogue for the new h. Runs EVERY step (incl. t=0).
// ---------------------------------------------------------------------------
__global__ __launch_bounds__(256) void k_gates_lstm(
    const float* __restrict__ inp, const float* __restrict__ hcur,
    const float* __restrict__ W_ih, const float* __restrict__ W_hh,
    const float* __restrict__ b_ih, const float* __restrict__ b_hh,
    float* __restrict__ c, float* __restrict__ hnxt,
    unsigned short* __restrict__ hsp1, unsigned short* __restrict__ hsp2) {
    __shared__ float xs[16 * 384];
    __shared__ float wt[32 * 260];      // reused as gl[16*256] for the exchange
    const int tid = threadIdx.x;
    const int r0 = blockIdx.x * 16;
    const int u0 = blockIdx.y * 64;

#pragma unroll
    for (int p = 0; p < 2; p++) {               // stage inp [16][128] -> cols [0,128)
        int ff = tid + 256 * p, row = ff >> 5, c4 = ff & 31;
        *(float4*)&xs[row * 384 + c4 * 4] =
            *(const float4*)(inp + (size_t)(r0 + row) * 128 + c4 * 4);
    }
#pragma unroll
    for (int p = 0; p < 4; p++) {               // stage h [16][256] -> cols [128,384)
        int ff = tid + 256 * p, row = ff >> 6, c4 = ff & 63;
        *(float4*)&xs[row * 384 + 128 + c4 * 4] =
            *(const float4*)(hcur + (size_t)(r0 + row) * 256 + c4 * 4);
    }
    const int g = tid >> 6, l = tid & 63;
    float acc[4][4] = {{0.f}};

    for (int kc = 0; kc < 12; kc++) {
        __syncthreads();
        {
            const float* src; int rowlen, koff;
            if (kc < 4) { src = W_ih; rowlen = 128; koff = kc * 32; }
            else        { src = W_hh; rowlen = 256; koff = (kc - 4) * 32; }
#pragma unroll
            for (int p = 0; p < 8; p++) {
                int rl = (tid >> 3) + 32 * p;   // row_local 0..255
                int k4 = tid & 7;
                int grow = ((rl >> 6) << 8) + u0 + (rl & 63);
                float4 w = *(const float4*)(src + (size_t)grow * rowlen + koff + k4 * 4);
                wt[(k4 * 4 + 0) * 260 + rl] = w.x;
                wt[(k4 * 4 + 1) * 260 + rl] = w.y;
                wt[(k4 * 4 + 2) * 260 + rl] = w.z;
                wt[(k4 * 4 + 3) * 260 + rl] = w.w;
            }
        }
        __syncthreads();
#pragma unroll
        for (int kk = 0; kk < 32; kk += 4) {
            float4 w0 = *(const float4*)&wt[(kk + 0) * 260 + 4 * l];
            float4 w1 = *(const float4*)&wt[(kk + 1) * 260 + 4 * l];
            float4 w2 = *(const float4*)&wt[(kk + 2) * 260 + 4 * l];
            float4 w3 = *(const float4*)&wt[(kk + 3) * 260 + 4 * l];
#pragma unroll
            for (int b = 0; b < 4; b++) {
                float4 xb = *(const float4*)&xs[(4 * g + b) * 384 + kc * 32 + kk];
                acc[b][0] = fmaf(xb.w, w3.x, fmaf(xb.z, w2.x, fmaf(xb.y, w1.x, fmaf(xb.x, w0.x, acc[b][0]))));
                acc[b][1] = fmaf(xb.w, w3.y, fmaf(xb.z, w2.y, fmaf(xb.y, w1.y, fmaf(xb.x, w0.y, acc[b][1]))));
                acc[b][2] = fmaf(xb.w, w3.z, fmaf(xb.z, w2.z, fmaf(xb.y, w1.z, fmaf(xb.x, w0.z, acc[b][2]))));
                acc[b][3] = fmaf(xb.w, w3.w, fmaf(xb.z, w2.w, fmaf(xb.y, w1.w, fmaf(xb.x, w0.w, acc[b][3]))));
            }
        }
    }
    {
        int rl0 = 4 * l;
        int grow0 = ((rl0 >> 6) << 8) + u0 + (rl0 & 63);
        float4 bi = *(const float4*)(b_ih + grow0);
        float4 bh = *(const float4*)(b_hh + grow0);
#pragma unroll
        for (int b = 0; b < 4; b++) {
            acc[b][0] += bi.x + bh.x; acc[b][1] += bi.y + bh.y;
            acc[b][2] += bi.z + bh.z; acc[b][3] += bi.w + bh.w;
        }
    }
    __syncthreads();
    float* gl = wt;                              // [16][256]: gate*64+ul per row
#pragma unroll
    for (int b = 0; b < 4; b++)
        *(float4*)&gl[(4 * g + b) * 256 + 4 * l] =
            make_float4(acc[b][0], acc[b][1], acc[b][2], acc[b][3]);
    __syncthreads();
    {   // LSTM pointwise: thread -> (bl = tid>>4, 4 u's)
        int bl = tid >> 4, uq = tid & 15;
        size_t cidx = (size_t)(r0 + bl) * 256 + u0 + uq * 4;
        float4 cold4 = *(float4*)(c + cidx);
        float4 cv, hv;
#pragma unroll
        for (int j = 0; j < 4; j++) {
            int ul = uq * 4 + j;
            float gi = gl[bl * 256 + ul];
            float gf = gl[bl * 256 + 64 + ul];
            float gg = gl[bl * 256 + 128 + ul];
            float go = gl[bl * 256 + 192 + ul];
            float si = fmaf(0.5f, tanhf(0.5f * gi), 0.5f);
            float sf = fmaf(0.5f, tanhf(0.5f * gf), 0.5f);
            float so = fmaf(0.5f, tanhf(0.5f * go), 0.5f);
            float tg = tanhf(gg);
            float cold = (&cold4.x)[j];
            float cn = sf * cold + si * tg;
            (&cv.x)[j] = cn;
            (&hv.x)[j] = so * tanhf(cn);
        }
        *(float4*)(c + cidx) = cv;
        *(float4*)(hnxt + cidx) = hv;
        ushort4 p1, p2;
        split2h(hv.x, p1.x, p2.x);
        split2h(hv.y, p1.y, p2.y);
        split2h(hv.z, p1.z, p2.z);
        split2h(hv.w, p1.w, p2.w);
        *(ushort4*)(hsp1 + cidx) = p1;
        *(ushort4*)(hsp2 + cidx) = p2;
    }
}

// ---------------------------------------------------------------------------
// W-stationary, V-MAJOR fused logits + gumbel + per-(tile,row) partials.
// MFMA operand swap vs round 7: D = W(A) x h(B) -> D[m=quad*4+reg = v-local]
// [n=n4 = row]. A thread now owns 4 v's for ONE row per set: stats merge is
// in-thread VALU + a 2-step quad butterfly (10 shuffles per set per rg,
// was 200) — removes the round-7 DS-pipe latency wall.
// lg is BIT-IDENTICAL to rounds 4/7: products commute, MFMA k-tree is
// positional, chain order (h1w1 x8 | h1w2, h2w1 per kc) preserved.
// ---------------------------------------------------------------------------
__global__ __launch_bounds__(256, 4) void k_logits_sample(
    const unsigned short* __restrict__ hsp1, const unsigned short* __restrict__ hsp2,
    const float* __restrict__ W_out, const float* __restrict__ b_out,
    unsigned key0, unsigned key1, float* __restrict__ part) {
    __shared__ float red[4][32][5];
    const int tid = threadIdx.x;
    const int w = tid >> 6, lane = tid & 63;
    const int quad = lane >> 4, n4 = lane & 15;
    const int tile = blockIdx.x % NT64;
    const int q    = blockIdx.x / NT64;
    const int vfrag = tile * 64 + w * 16 + n4;         // W A-frag row (m=n4)
    const int vown0 = tile * 64 + w * 16 + quad * 4;   // thread's 4 D v's

    // ---- W A-fragments: load fp32, split to two f16 planes, keep in regs ----
    half8 w1[8], w2[8];
#pragma unroll
    for (int kc = 0; kc < 8; kc++) {
        const float* wp = W_out + (size_t)vfrag * 256 + kc * 32 + quad * 8;
        float4 wa = *(const float4*)wp;
        float4 wb = *(const float4*)(wp + 4);
        float wv[8] = {wa.x, wa.y, wa.z, wa.w, wb.x, wb.y, wb.z, wb.w};
#pragma unroll
        for (int j = 0; j < 8; j++) {
            _Float16 hi = (_Float16)wv[j];
            float r = (wv[j] - (float)hi) * RSCALE;
            w1[kc][j] = hi;
            w2[kc][j] = (_Float16)r;
        }
    }
    const float4 bo4 = *(const float4*)(b_out + vown0);

#pragma unroll 1
    for (int rg = 0; rg < 32; rg++) {
        const int r0 = q * 1024 + rg * 32;
        f32x4 ah[2], al[2];                      // [set]: rows r0+set*16+n4
#pragma unroll
        for (int s = 0; s < 2; s++) {
            ah[s] = (f32x4){0.f, 0.f, 0.f, 0.f};
            al[s] = (f32x4){0.f, 0.f, 0.f, 0.f};
        }
#pragma unroll
        for (int kc = 0; kc < 8; kc++) {
            // h B-frags straight from global (L2-hot): B[n=n4][k=quad*8+j]
            size_t abase = (size_t)(r0 + n4) * 256 + kc * 32 + quad * 8;
            half8 h1s0 = *(const half8*)(hsp1 + abase);
            half8 h1s1 = *(const half8*)(hsp1 + abase + 16 * 256);
            half8 h2s0 = *(const half8*)(hsp2 + abase);
            half8 h2s1 = *(const half8*)(hsp2 + abase + 16 * 256);
            ah[0] = __builtin_amdgcn_mfma_f32_16x16x32_f16(w1[kc], h1s0, ah[0], 0, 0, 0);
            al[0] = __builtin_amdgcn_mfma_f32_16x16x32_f16(w2[kc], h1s0, al[0], 0, 0, 0);
            al[0] = __builtin_amdgcn_mfma_f32_16x16x32_f16(w1[kc], h2s0, al[0], 0, 0, 0);
            ah[1] = __builtin_amdgcn_mfma_f32_16x16x32_f16(w1[kc], h1s1, ah[1], 0, 0, 0);
            al[1] = __builtin_amdgcn_mfma_f32_16x16x32_f16(w2[kc], h1s1, al[1], 0, 0, 0);
            al[1] = __builtin_amdgcn_mfma_f32_16x16x32_f16(w1[kc], h2s1, al[1], 0, 0, 0);
        }
        // ---- epilogue: in-thread merge over 4 v's, 2-step quad butterfly ----
#pragma unroll
        for (int s = 0; s < 2; s++) {
            const unsigned row = (unsigned)(r0 + s * 16 + n4);
            float ss = 0.f, tss = 0.f, us = -3.4e38f, las = 0.f; int ais = 0;
#pragma unroll
            for (int j = 0; j < 4; j++) {
                float lg = fmaf(RINV, al[s][j], ah[s][j]) + (&bo4.x)[j];
                float e = __expf(lg - 20.f);
                ss += e;
                tss = fmaf(e, lg, tss);
                const int v = vown0 + j;
                unsigned o0, o1;
                tf2x32(key0, key1, 0u, row * (unsigned)V + (unsigned)v, o0, o1);
                unsigned bits = o0 ^ o1;
                float f = __uint_as_float((bits >> 9) | 0x3f800000u) - 1.0f;
                float uu = fmaxf(1.17549435e-38f, f + 1.17549435e-38f);
                float gmb = -logf(-logf(uu));
                float ut = lg + gmb;
                if (ut > us || (ut == us && v < ais)) { us = ut; ais = v; las = lg; }
            }
            // butterfly across the 4 quads holding the same row
#pragma unroll
            for (int off = 16; off < 64; off <<= 1) {
                ss  += __shfl_xor(ss, off);
                tss += __shfl_xor(tss, off);
                float u2 = __shfl_xor(us, off);
                float la2 = __shfl_xor(las, off);
                int a2 = __shfl_xor(ais, off);
                if (u2 > us || (u2 == us && a2 < ais)) { us = u2; ais = a2; las = la2; }
            }
            if (quad == 0) {
                int rl = s * 16 + n4;
                red[w][rl][0] = ss;
                red[w][rl][1] = tss;
                red[w][rl][2] = us;
                red[w][rl][3] = las;
                ((int*)red[w][rl])[4] = ais;
            }
        }
        __syncthreads();
        if (tid < 32) {
            float s = red[0][tid][0] + red[1][tid][0] + red[2][tid][0] + red[3][tid][0];
            float ts = red[0][tid][1] + red[1][tid][1] + red[2][tid][1] + red[3][tid][1];
            float ut = red[0][tid][2];
            float la = red[0][tid][3];
            int ai = ((int*)red[0][tid])[4];
#pragma unroll
            for (int w2 = 1; w2 < 4; w2++) {
                float u2 = red[w2][tid][2];
                int a2 = ((int*)red[w2][tid])[4];
                if (u2 > ut || (u2 == ut && a2 < ai)) {
                    ut = u2; ai = a2; la = red[w2][tid][3];
                }
            }
            float* p = part + (size_t)(r0 + tid) * PROWSTR + tile * PSTR;
            p[0] = s; p[1] = ts; p[2] = ut; p[3] = la;
            ((int*)p)[4] = ai;
        }
        __syncthreads();
    }
}

// ---------------------------------------------------------------------------
// Combine NT64 partials per row -> sample, logp, entropy, emb gather.
// block: 8 rows x 32 lanes; lane-split slots + 32-lane butterfly.
// ---------------------------------------------------------------------------
__global__ __launch_bounds__(256) void k_sample_out(
    const float* __restrict__ part, const float* __restrict__ emb,
    float* __restrict__ inp, float* __restrict__ out, int step) {
    const int tid = threadIdx.x;
    const int row = blockIdx.x * 8 + (tid >> 5);
    const int lane = tid & 31;
    const float* p = part + (size_t)row * PROWSTR;
    float s = 0.f, ts = 0.f, ut = -3.4e38f, la = 0.f; int a = 0;
    for (int cg = lane; cg < NT64; cg += 32) {
        const float* qq = p + cg * PSTR;
        s += qq[0]; ts += qq[1];
        float uc = qq[2]; int ac = ((const int*)qq)[4];
        if (uc > ut || (uc == ut && ac < a)) { ut = uc; a = ac; la = qq[3]; }
    }
#pragma unroll
    for (int off = 1; off < 32; off <<= 1) {
        s  += __shfl_xor(s, off);
        ts += __shfl_xor(ts, off);
        float u2 = __shfl_xor(ut, off);
        float la2 = __shfl_xor(la, off);
        int a2 = __shfl_xor(a, off);
        if (u2 > ut || (u2 == ut && a2 < a)) { ut = u2; a = a2; la = la2; }
    }
    float lse = logf(s) + 20.f;
    if (lane == 0) {
        out[(size_t)row * OC + step] = (float)a;
        out[(size_t)B * OC + (size_t)row * OC + step] = la - lse;
        out[(size_t)2 * B * OC + (size_t)row * OC + step] = lse - ts / s;
    }
    float4 e4 = *(const float4*)(emb + (size_t)a * 128 + lane * 4);
    *(float4*)&inp[(size_t)row * 128 + lane * 4] = e4;
}

// ---------------------------------------------------------------------------
// Host — LSTM cell runs EVERY step (incl. t=0), then logits from the NEW h.
// ---------------------------------------------------------------------------
extern "C" void kernel_launch(void* const* d_in, const int* in_sizes, int n_in,
                              void* d_out, int out_size, void* d_ws, size_t ws_size,
                              hipStream_t stream) {
    (void)in_sizes; (void)n_in; (void)out_size; (void)ws_size;
    const float* x     = (const float*)d_in[0];
    const float* W_in  = (const float*)d_in[1];
    const float* b_in  = (const float*)d_in[2];
    const float* W_out = (const float*)d_in[3];
    const float* b_out = (const float*)d_in[4];
    const float* emb   = (const float*)d_in[5];
    const float* sos   = (const float*)d_in[6];
    const float* W_ih  = (const float*)d_in[7];
    const float* W_hh  = (const float*)d_in[8];
    const float* b_ih  = (const float*)d_in[9];
    const float* b_hh  = (const float*)d_in[10];
    float* out = (float*)d_out;
    float* ws  = (float*)d_ws;

    float* hA   = ws;                                   // B*H f32
    float* hB   = ws + 1048576;                         // B*H f32
    float* cc   = ws + 2097152;                         // B*H f32
    float* inp  = ws + 3145728;                         // B*E f32
    float* part = ws + 3670016;                         // B * PROWSTR f32 = 12.288M
    unsigned short* hsp1 = (unsigned short*)(ws + 15958016);  // B*H ushort
    unsigned short* hsp2 = (unsigned short*)(ws + 16482304);  // B*H ushort

    // step keys: foldlike split of key(42) = (0,42): key_t = block at (0, t)
    unsigned K0[TT], K1[TT];
    for (int t = 0; t < TT; t++) {
        uint32_t o0, o1;
        tf2x32(0u, 42u, 0u, (uint32_t)t, o0, o1);
        K0[t] = o0; K1[t] = o1;
    }

    k_init<<<4096, 256, 0, stream>>>(cc, inp, sos, out);
    k_h0<<<B / 16, 256, 0, stream>>>(x, W_in, b_in, hA);

    float* hc = hA;
    float* hn = hB;
    for (int t = 0; t < TT; t++) {
        k_gates_lstm<<<dim3(B / 16, 4), 256, 0, stream>>>(inp, hc, W_ih, W_hh,
                                                          b_ih, b_hh, cc, hn, hsp1, hsp2);
        k_logits_sample<<<NT64 * RQ, 256, 0, stream>>>(hsp1, hsp2, W_out, b_out,
                                                       K0[t], K1[t], part);
        k_sample_out<<<B / 8, 256, 0, stream>>>(part, emb, inp, out, t);
        float* tmp = hc; hc = hn; hn = tmp;
    }
}